// Round 3
// baseline (148.762 us; speedup 1.0000x reference)
//
#include <hip/hip_runtime.h>
#include <math.h>

#define VOCAB 50000
#define D_WORD 300
#define D_TOPIC 128
#define DH 312            // D_NOUN_HIDDEN
#define NB 8192
#define LMAX 32
#define N_MONTH 12

// ---------------------------------------------------------------------------
// Kernel 1 (tiny): w = k_w^T @ (q_w @ topic_emb + q_b).  One block.
// k_b and the month one-hot cancel in the softmax, so only w[0:300] feeds
// scores; computing all 312 is harmless.
// ---------------------------------------------------------------------------
__global__ __launch_bounds__(320) void compute_w_kernel(
    const float* __restrict__ topic_emb,
    const float* __restrict__ q_w, const float* __restrict__ q_b,
    const float* __restrict__ k_w,
    float* __restrict__ w_out)
{
    __shared__ float query_s[D_TOPIC];
    int t = threadIdx.x;
    if (t < D_TOPIC) {
        float q = q_b[t];
        for (int k = 0; k < D_TOPIC; ++k)
            q = fmaf(q_w[t * D_TOPIC + k], topic_emb[k], q);
        query_s[t] = q;
    }
    __syncthreads();
    if (t < DH) {
        float acc = 0.f;
        for (int d = 0; d < D_TOPIC; ++d)
            acc = fmaf(k_w[d * DH + t], query_s[d], acc);   // coalesced over t
        w_out[t] = acc;
    }
}

// ---------------------------------------------------------------------------
// Kernel 2: s_vocab[v] = (we[v,0:300] . w[0:300]) * 1/sqrt(128)  (pre-scaled
// so the attn kernel skips the multiply).  One wave per row, float4 loads
// (row pitch 1200 B = 75 x 16 B, 16B-aligned), shuffle reduce.
// ---------------------------------------------------------------------------
__global__ __launch_bounds__(256) void vocab_score_kernel(
    const float* __restrict__ we, const float* __restrict__ w,
    float* __restrict__ s_vocab)
{
    __shared__ float4 w4[75];
    int t = threadIdx.x;
    if (t < 75) w4[t] = ((const float4*)w)[t];
    __syncthreads();
    int wave = t >> 6, lane = t & 63;
    int row = blockIdx.x * 4 + wave;
    if (row >= VOCAB) return;
    const float4* r = (const float4*)(we + (size_t)row * D_WORD);
    float4 a = r[lane];
    float4 ww = w4[lane];
    float p = fmaf(a.x, ww.x, fmaf(a.y, ww.y, fmaf(a.z, ww.z, a.w * ww.w)));
    if (lane < 11) {
        float4 b = r[64 + lane];
        float4 wb = w4[64 + lane];
        p = fmaf(b.x, wb.x, fmaf(b.y, wb.y, fmaf(b.z, wb.z, fmaf(b.w, wb.w, p))));
    }
    #pragma unroll
    for (int off = 32; off > 0; off >>= 1)
        p += __shfl_xor(p, off);
    if (lane == 0) s_vocab[row] = p * 0.08838834764831845f;  // 1/sqrt(128)
}

// ---------------------------------------------------------------------------
// Kernel 3: TWO waves per sample (length-balancing).  Lengths ~U[0,32]; with
// 1 wave/sample every CU carries a len~32 tail wave.  Each wave redundantly
// computes the softmax (cheap: 32 gathered scalars + shuffles), then
// accumulates only its half of the tokens (<=16 rows).  half==1 dumps its
// partial into LDS; half==0 adds and stores.  No divergent barriers: every
// wave reaches the single __syncthreads.
// Block = 256 thr = 4 waves = 2 samples; grid = NB/2.
// ---------------------------------------------------------------------------
__global__ __launch_bounds__(256) void attn_kernel(
    const int* __restrict__ noun_ids, const int* __restrict__ lengths,
    const int* __restrict__ months, const int* __restrict__ encode_p,
    const float* __restrict__ we, const float* __restrict__ s_vocab,
    float* __restrict__ out)
{
    __shared__ float4 part[2][76];        // 75 used, +1 pad
    int wave = threadIdx.x >> 6, lane = threadIdx.x & 63;
    int pair = wave >> 1, half = wave & 1;
    int b = blockIdx.x * 2 + pair;
    int len = lengths[b];
    if (len > LMAX) len = LMAX;
    bool valid = (len > 0);

    float4 acc0 = {0.f, 0.f, 0.f, 0.f};
    float4 acc1 = {0.f, 0.f, 0.f, 0.f};
    float p = 0.f;   // this lane's attn weight (lanes < len)
    int id = 0;

    if (valid) {
        float sc = -INFINITY;
        if (lane < LMAX) {
            id = noun_ids[b * LMAX + lane];
            if (lane < len) sc = s_vocab[id];          // pre-scaled
        }
        float m = sc;
        #pragma unroll
        for (int off = 32; off > 0; off >>= 1) m = fmaxf(m, __shfl_xor(m, off));
        float e = (lane < len) ? __expf(sc - m) : 0.f;
        float s = e;
        #pragma unroll
        for (int off = 32; off > 0; off >>= 1) s += __shfl_xor(s, off);
        p = e * (1.f / s);

        int h  = (len + 1) >> 1;
        int l0 = half ? h : 0;
        int l1 = half ? len : h;
        for (int l = l0; l < l1; ++l) {
            float a  = __shfl(p, l);
            int  rid = __shfl(id, l);
            const float4* r = (const float4*)(we + (size_t)rid * D_WORD);
            float4 v = r[lane];
            acc0.x = fmaf(a, v.x, acc0.x);
            acc0.y = fmaf(a, v.y, acc0.y);
            acc0.z = fmaf(a, v.z, acc0.z);
            acc0.w = fmaf(a, v.w, acc0.w);
            if (lane < 11) {
                float4 v1 = r[64 + lane];
                acc1.x = fmaf(a, v1.x, acc1.x);
                acc1.y = fmaf(a, v1.y, acc1.y);
                acc1.z = fmaf(a, v1.z, acc1.z);
                acc1.w = fmaf(a, v1.w, acc1.w);
            }
        }
    }

    if (half == 1) {                       // publish partial (zeros if !valid)
        part[pair][lane] = acc0;
        if (lane < 11) part[pair][64 + lane] = acc1;
    }
    __syncthreads();                       // all 4 waves always arrive

    if (half == 0) {
        float4* ob = (float4*)(out + (size_t)b * DH);   // 78 float4, 16B-aligned
        float4 q0 = part[pair][lane];
        acc0.x += q0.x; acc0.y += q0.y; acc0.z += q0.z; acc0.w += q0.w;
        ob[lane] = acc0;                   // zeros when !valid (poison overwrite)
        if (lane < 11) {
            float4 q1 = part[pair][64 + lane];
            acc1.x += q1.x; acc1.y += q1.y; acc1.z += q1.z; acc1.w += q1.w;
            ob[64 + lane] = acc1;
        } else if (lane < 14) {
            int mo = months[b];
            float enc = valid ? (float)(*encode_p) : 0.f;
            int base = (lane - 11) * 4;
            float4 oh;
            oh.x = (base + 0 == mo) ? enc : 0.f;
            oh.y = (base + 1 == mo) ? enc : 0.f;
            oh.z = (base + 2 == mo) ? enc : 0.f;
            oh.w = (base + 3 == mo) ? enc : 0.f;
            ob[64 + lane] = oh;
        }
    }
}

// ---------------------------------------------------------------------------
extern "C" void kernel_launch(void* const* d_in, const int* in_sizes, int n_in,
                              void* d_out, int out_size, void* d_ws, size_t ws_size,
                              hipStream_t stream) {
    const float* topic_emb = (const float*)d_in[0];
    const int*   noun_ids  = (const int*)d_in[1];
    const int*   lengths   = (const int*)d_in[2];
    const int*   months    = (const int*)d_in[3];
    const int*   encode    = (const int*)d_in[4];
    const float* we        = (const float*)d_in[5];
    const float* k_w       = (const float*)d_in[6];
    // d_in[7] = k_b: cancels in softmax, never touches `value` -> unused.
    const float* q_w       = (const float*)d_in[8];
    const float* q_b       = (const float*)d_in[9];
    float* out = (float*)d_out;

    float* w_vec   = (float*)d_ws;       // 312 floats (padded to 512)
    float* s_vocab = w_vec + 512;        // 50000 floats (~202 KB total ws)

    compute_w_kernel<<<1, 320, 0, stream>>>(topic_emb, q_w, q_b, k_w, w_vec);
    vocab_score_kernel<<<(VOCAB + 3) / 4, 256, 0, stream>>>(we, w_vec, s_vocab);
    attn_kernel<<<NB / 2, 256, 0, stream>>>(noun_ids, lengths, months, encode,
                                            we, s_vocab, out);
}

// Round 4
// 138.868 us; speedup vs baseline: 1.0713x; 1.0713x over previous
//
#include <hip/hip_runtime.h>
#include <math.h>

#define VOCAB 50000
#define D_WORD 300
#define D_TOPIC 128
#define DH 312            // D_NOUN_HIDDEN
#define NB 8192
#define LMAX 32
#define N_MONTH 12

// ---------------------------------------------------------------------------
// Kernel 1 (tiny): w = (k_w^T @ (q_w @ topic_emb + q_b)) * 1/sqrt(128).
// One block.  k_b and the month one-hot cancel in the softmax, so only
// w[0:300] feeds scores; the 1/sqrt(d_topic) score scale is folded in here.
// ---------------------------------------------------------------------------
__global__ __launch_bounds__(320) void compute_w_kernel(
    const float* __restrict__ topic_emb,
    const float* __restrict__ q_w, const float* __restrict__ q_b,
    const float* __restrict__ k_w,
    float* __restrict__ w_out)
{
    __shared__ float query_s[D_TOPIC];
    int t = threadIdx.x;
    if (t < D_TOPIC) {
        float q = q_b[t];
        for (int k = 0; k < D_TOPIC; ++k)
            q = fmaf(q_w[t * D_TOPIC + k], topic_emb[k], q);
        query_s[t] = q;
    }
    __syncthreads();
    if (t < DH) {
        float acc = 0.f;
        for (int d = 0; d < D_TOPIC; ++d)
            acc = fmaf(k_w[d * DH + t], query_s[d], acc);   // coalesced over t
        w_out[t] = acc * 0.08838834764831845f;              // 1/sqrt(128)
    }
}

// ---------------------------------------------------------------------------
// Kernel 2 (fused, single pass): one WAVE per sample, online softmax.
// Per token: read we[id] row ONCE (float4: lane covers cols [4L,4L+4),
// lanes<11 also [256+4L,...)), score it inline against w (shuffle-reduce),
// then flash-style rescale-accumulate.  No vocab sweep, no s_vocab buffer,
// no LDS, no barriers.  Month one-hot columns written directly (softmax
// sums to 1, so out[:,300+m] == encode * onehot(month)).
// ---------------------------------------------------------------------------
__global__ __launch_bounds__(256) void attn_fused_kernel(
    const int* __restrict__ noun_ids, const int* __restrict__ lengths,
    const int* __restrict__ months, const int* __restrict__ encode_p,
    const float* __restrict__ we, const float* __restrict__ w,
    float* __restrict__ out)
{
    int wave = threadIdx.x >> 6, lane = threadIdx.x & 63;
    int b = blockIdx.x * 4 + wave;
    float4* ob = (float4*)(out + (size_t)b * DH);   // 78 float4, 16B-aligned
    int len = lengths[b];

    if (len <= 0) {                       // reference leaves empty rows zero;
        float4 z = {0.f, 0.f, 0.f, 0.f};  // d_out is poisoned -> must write
        ob[lane] = z;
        if (lane < 14) ob[64 + lane] = z;
        return;                           // len uniform per wave: no divergence
    }
    if (len > LMAX) len = LMAX;

    // w fragment in registers (same cols as this lane's row fragment)
    const float4* w4 = (const float4*)w;
    float4 ww = w4[lane];
    float4 wb = (lane < 11) ? w4[64 + lane] : (float4){0.f, 0.f, 0.f, 0.f};

    int id = (lane < LMAX) ? noun_ids[b * LMAX + lane] : 0;

    float m = -1e30f, denom = 0.f;        // online-softmax state
    float4 acc0 = {0.f, 0.f, 0.f, 0.f};
    float4 acc1 = {0.f, 0.f, 0.f, 0.f};

    for (int l = 0; l < len; ++l) {
        int rid = __shfl(id, l);
        const float4* r = (const float4*)(we + (size_t)rid * D_WORD);
        float4 v0 = r[lane];
        float4 v1 = (lane < 11) ? r[64 + lane] : (float4){0.f, 0.f, 0.f, 0.f};
        // inline score: dot(row, w)  (w pre-scaled by 1/sqrt(128))
        float p = fmaf(v0.x, ww.x, fmaf(v0.y, ww.y,
                  fmaf(v0.z, ww.z, fmaf(v0.w, ww.w,
                  fmaf(v1.x, wb.x, fmaf(v1.y, wb.y,
                  fmaf(v1.z, wb.z, v1.w * wb.w)))))));
        #pragma unroll
        for (int off = 32; off > 0; off >>= 1)
            p += __shfl_xor(p, off);      // s broadcast to all lanes
        // flash rescale-accumulate
        float mn = fmaxf(m, p);
        float c  = __expf(m - mn);        // 0 on first iter (m = -1e30)
        float e  = __expf(p - mn);
        m = mn;
        denom = fmaf(denom, c, e);
        acc0.x = fmaf(acc0.x, c, e * v0.x);
        acc0.y = fmaf(acc0.y, c, e * v0.y);
        acc0.z = fmaf(acc0.z, c, e * v0.z);
        acc0.w = fmaf(acc0.w, c, e * v0.w);
        acc1.x = fmaf(acc1.x, c, e * v1.x);
        acc1.y = fmaf(acc1.y, c, e * v1.y);
        acc1.z = fmaf(acc1.z, c, e * v1.z);
        acc1.w = fmaf(acc1.w, c, e * v1.w);
    }

    float rs = 1.f / denom;
    acc0.x *= rs; acc0.y *= rs; acc0.z *= rs; acc0.w *= rs;
    ob[lane] = acc0;
    if (lane < 11) {
        acc1.x *= rs; acc1.y *= rs; acc1.z *= rs; acc1.w *= rs;
        ob[64 + lane] = acc1;
    } else if (lane < 14) {
        int mo = months[b];
        float enc = (float)(*encode_p);
        int base = (lane - 11) * 4;
        float4 oh;
        oh.x = (base + 0 == mo) ? enc : 0.f;
        oh.y = (base + 1 == mo) ? enc : 0.f;
        oh.z = (base + 2 == mo) ? enc : 0.f;
        oh.w = (base + 3 == mo) ? enc : 0.f;
        ob[64 + lane] = oh;
    }
}

// ---------------------------------------------------------------------------
extern "C" void kernel_launch(void* const* d_in, const int* in_sizes, int n_in,
                              void* d_out, int out_size, void* d_ws, size_t ws_size,
                              hipStream_t stream) {
    const float* topic_emb = (const float*)d_in[0];
    const int*   noun_ids  = (const int*)d_in[1];
    const int*   lengths   = (const int*)d_in[2];
    const int*   months    = (const int*)d_in[3];
    const int*   encode    = (const int*)d_in[4];
    const float* we        = (const float*)d_in[5];
    const float* k_w       = (const float*)d_in[6];
    // d_in[7] = k_b: cancels in softmax, never touches `value` -> unused.
    const float* q_w       = (const float*)d_in[8];
    const float* q_b       = (const float*)d_in[9];
    float* out = (float*)d_out;

    float* w_vec = (float*)d_ws;         // 312 floats

    compute_w_kernel<<<1, 320, 0, stream>>>(topic_emb, q_w, q_b, k_w, w_vec);
    attn_fused_kernel<<<NB / 4, 256, 0, stream>>>(noun_ids, lengths, months,
                                                  encode, we, w_vec, out);
}